// Round 16
// baseline (1912.154 us; speedup 1.0000x reference)
//
#include <hip/hip_runtime.h>

// LSTM  B=64 T=512 D=256 H=512, fp32 in/out.
// R14 = R13 (fan-in-16 clusters) with the cross-wave gate race FIXED by
// making the gate mapping in-wave again (R6's invariant):
//   wave wv owns gemm cols {wv*16..+15} (LDS tile) u {64+wv*16..+15} (VGPR
//   tile) = h-cols {wv*4..+3} u {16+wv*4..+3}. lane -> (batch=lane>>3,
//   hsel=lane&7) reads ONLY gate_lds[wv] -> lgkmcnt(0) suffices, no barrier.
// 8 clusters x 16 WGs (128 WGs), 8 batches/cluster, 32 h-cols/WG. Weights
// hybrid: ct 0-3 LDS-resident, ct 4-7 in VGPRs (two-phase repack).
// Protocol = R6/R12 proven: publish u32 pairs -> vmcnt(0) [publish only] ->
// barrier A -> per-WG flag -> out + x-issue off-path -> single-64B-line
// sleep-paced poll (lanes<16, divergent exit) -> 8-u32 coalesced gather ->
// unpack + zbuild -> barrier B. 2 barriers/step.

#define T_   512
#define D_   256
#define H_   512
#define NCL  8            // clusters
#define WPC  16           // workgroups per cluster
#define BPC  8            // batches per cluster
#define NKT  24           // K tiles of 32 (24*32 = 768 = D_+H_)
#define ZW   768          // z row width in u16 (XOR-swizzled, no pad)

typedef __attribute__((ext_vector_type(8)))  short  short8;
typedef __attribute__((ext_vector_type(4)))  float  f32x4;
typedef __attribute__((ext_vector_type(4)))  float  float4_;
typedef unsigned short ushort_t;
typedef unsigned int   uint_t;

__device__ __forceinline__ ushort_t f2bf(float f) {           // RNE f32->bf16
    unsigned int u = __float_as_uint(f);
    u += 0x7FFFu + ((u >> 16) & 1u);
    return (ushort_t)(u >> 16);
}
__device__ __forceinline__ float sigm_(float x) { return 1.0f / (1.0f + __expf(-x)); }
__device__ __forceinline__ float tanh_(float x) {
    float a = fabsf(x);
    float e = __expf(-2.0f * a);
    float r = (1.0f - e) / (1.0f + e);
    return copysignf(r, x);
}

// z swizzle: (row r, col c) at u16 index r*ZW + (((c>>3) ^ (r&7))<<3) + (c&7)

__global__ __launch_bounds__(256, 1)
void lstm_persistent(const float* __restrict__ x,
                     const float* __restrict__ Wf, const float* __restrict__ bf_,
                     const float* __restrict__ Wi, const float* __restrict__ bi_,
                     const float* __restrict__ Wo, const float* __restrict__ bo_,
                     const float* __restrict__ Wc, const float* __restrict__ bc_,
                     float* __restrict__ out,
                     uint_t* __restrict__ flags,   // [NCL][WPC] per-WG, monotonic
                     uint_t* __restrict__ hexch)   // [2][NCL][BPC][256] u32 {h1<<16|h0}
{
    __shared__ ushort_t w_lds[4 * NKT * 512];     // 98304 B (ct 0-3 at runtime)
    __shared__ ushort_t z2[2][16 * ZW];           // 49152 B (z ping-pong, swizzled)
    __shared__ float    gate_lds[4][2][16][12];   //  6144 B (PER-WAVE transpose)
    __shared__ float    bias_lds[128];            //   512 B   (total 154112)

    const int tid  = threadIdx.x;
    const int lane = tid & 63;
    const int wv   = tid >> 6;          // wave 0..3
    const int cl   = blockIdx.x >> 4;   // cluster 0..7
    const int w    = blockIdx.x & 15;   // wg-in-cluster 0..15
    const int b0   = cl * BPC;          // first batch
    const int hc0  = w * 32;            // first h-col (global)

    // ---- zero both z buffers (rows 8..15 stay zero forever; h(0)=0) ----
    {
        uint_t* zz = (uint_t*)z2;
        for (int i = tid; i < 2 * 16 * ZW / 2; i += 256) zz[i] = 0;
    }

    // ---- repack phase A: col-tiles 4..7 -> w_lds (B-frag order) ----
    // frag: lane l holds B[k = kt*32 + (l>>4)*8 + jj][n = ct*16 + (l&15)]
#define REPACK(CT_BASE)                                                        \
    for (int idx = tid; idx < 4 * NKT * 64; idx += 256) {                      \
        int blk   = idx >> 6;            /* 0..95 */                           \
        int ln    = idx & 63;                                                  \
        int ct    = (CT_BASE) + blk / NKT;                                     \
        int kt    = blk % NKT;                                                 \
        int j     = ct * 16 + (ln & 15); /* gemm col 0..127 */                 \
        int hc    = j >> 2, g = j & 3;                                         \
        int gcol  = hc0 + hc;                                                  \
        const float* Wsrc = (g == 0) ? Wf : ((g == 1) ? Wi                     \
                            : ((g == 2) ? Wo : Wc));                           \
        int krow0 = kt * 32 + (ln >> 4) * 8;                                   \
        short8 v;                                                              \
        _Pragma("unroll")                                                      \
        for (int jj = 0; jj < 8; ++jj)                                         \
            v[jj] = (short)f2bf(Wsrc[(size_t)(krow0 + jj) * H_ + gcol]);       \
        *(short8*)(w_lds + blk * 512 + ln * 8) = v;                            \
    }
    REPACK(4)
    __syncthreads();

    // ---- hoist col-tile (4+wv) into VGPRs ----
    short8 Bf[NKT];
#pragma unroll
    for (int kt = 0; kt < NKT; ++kt)
        Bf[kt] = *(const short8*)(w_lds + (wv * NKT + kt) * 512 + lane * 8);
    asm volatile("" ::: "memory");   // pin Bf in VGPRs
    __syncthreads();                 // all waves read before overwrite

    // ---- repack phase B: col-tiles 0..3 -> w_lds (runtime-resident) ----
    REPACK(0)
#undef REPACK
    if (tid < 128) {
        int g = tid & 3, hc = tid >> 2;   // bias_lds[j] = bias of gemm col j
        const float* bsrc = (g == 0) ? bf_ : ((g == 1) ? bi_ : ((g == 2) ? bo_ : bc_));
        bias_lds[tid] = bsrc[hc0 + hc];
    }

    // ---- persistent thread mappings ----
    const int bx = tid & 7, ch = tid >> 3;    // zbuild: row bx, x-block ch (0-31)
    const int l15 = lane & 15, lk = lane >> 4;
    // gates (IN-WAVE): lane -> (batch gb, h-col hc0+hcl)
    const int gb   = lane >> 3;               // batch 0..7
    const int hsel = lane & 7;
    const int hcl  = (hsel < 4) ? (wv * 4 + hsel) : (16 + wv * 4 + (hsel - 4));
    const int gtile = hsel >> 2;              // 0: LDS ct, 1: VGPR ct
    const int gcol4 = (hsel & 3) * 4;         // col base within wave tile
    const float* xbase = x + (size_t)(b0 + bx) * (T_ * D_) + ch * 8;

    // build z(0) x-part (rows 0-7; h region already zero)
    {
        const float4_* p = (const float4_*)xbase;
        float4_ x0 = p[0], x1 = p[1];
        short8 a;
#pragma unroll
        for (int e = 0; e < 4; ++e) {
            a[e]     = (short)f2bf(x0[e]);
            a[4 + e] = (short)f2bf(x1[e]);
        }
        *(short8*)(z2[0] + bx * ZW + ((ch ^ (bx & 7)) << 3)) = a;
    }
    __syncthreads();   // repack B, bias, z(0) ready

    uint_t* flags_cl = flags + cl * WPC;
    uint_t* hex0 = hexch + ((size_t)0 * NCL + cl) * (BPC * 256);
    uint_t* hex1 = hexch + ((size_t)1 * NCL + cl) * (BPC * 256);

    float c_reg = 0.0f;
    const int s7 = l15 & 7;
    const int blk0 = 32 + (tid >> 2), off2 = (tid & 3) * 2;   // gather unpack
    const size_t po = (size_t)gb * 256 + ((hc0 + hcl) >> 1);  // publish offset
    const ushort_t* wl = w_lds + (wv * NKT) * 512 + lane * 8; // LDS ct = wv
    float4_ xq0, xq1;

    for (int t = 0; t < T_; ++t) {
        // ---- MFMA: 24 kt x 2 col-tiles (LDS ct=wv, VGPR ct=4+wv); 4 chains ----
        const ushort_t* zr = z2[t & 1] + l15 * ZW;
        f32x4 aL0 = {0.f,0.f,0.f,0.f}, aL1 = {0.f,0.f,0.f,0.f};
        f32x4 aV0 = {0.f,0.f,0.f,0.f}, aV1 = {0.f,0.f,0.f,0.f};
#pragma unroll
        for (int kt = 0; kt < NKT; kt += 2) {
            short8 a0  = *(const short8*)(zr + ((((kt + 0) * 4 + lk) ^ s7) << 3));
            short8 a1  = *(const short8*)(zr + ((((kt + 1) * 4 + lk) ^ s7) << 3));
            short8 bl0 = *(const short8*)(wl + (kt + 0) * 512);
            short8 bl1 = *(const short8*)(wl + (kt + 1) * 512);
            aL0 = __builtin_amdgcn_mfma_f32_16x16x32_bf16(a0, bl0,        aL0, 0, 0, 0);
            aV0 = __builtin_amdgcn_mfma_f32_16x16x32_bf16(a0, Bf[kt + 0], aV0, 0, 0, 0);
            aL1 = __builtin_amdgcn_mfma_f32_16x16x32_bf16(a1, bl1,        aL1, 0, 0, 0);
            aV1 = __builtin_amdgcn_mfma_f32_16x16x32_bf16(a1, Bf[kt + 1], aV1, 0, 0, 0);
        }
        f32x4 accL = aL0 + aL1;   // C[batch=lk*4+i][gemm col wv*16 + l15]
        f32x4 accV = aV0 + aV1;   // C[batch=lk*4+i][gemm col 64 + wv*16 + l15]

        // ---- IN-WAVE transpose: wave wv writes & reads ONLY gate_lds[wv] ----
        if (lk < 2) {   // batches 0..7 only
            *(f32x4*)&gate_lds[wv][0][l15][lk * 4] = accL;
            *(f32x4*)&gate_lds[wv][1][l15][lk * 4] = accV;
        }
        asm volatile("s_waitcnt lgkmcnt(0)" ::: "memory");
        __builtin_amdgcn_sched_barrier(0);

        float pre[4];
#pragma unroll
        for (int g = 0; g < 4; ++g)
            pre[g] = bias_lds[hcl * 4 + g] + gate_lds[wv][gtile][gcol4 + g][gb];

        float fg = sigm_(pre[0]);
        float ig = sigm_(pre[1]);
        float og = sigm_(pre[2]);
        float cc = tanh_(pre[3]);
        c_reg = fmaf(c_reg, fg, cc * ig);
        float hout = og * tanh_(c_reg);

        // ---- publish h(t+1): packed u32 pair, even-hsel lanes (partner lane^1) ----
        float hpart = __shfl_xor(hout, 1);    // partner holds hcl^1
        if (!(hsel & 1)) {
            uint_t pk = ((uint_t)f2bf(hpart) << 16) | (uint_t)f2bf(hout);
            uint_t* hp = (((t + 1) & 1) ? hex1 : hex0) + po;
            __hip_atomic_store(hp, pk, __ATOMIC_RELAXED, __HIP_MEMORY_SCOPE_AGENT);
        }

        // ---- clean drain: ONLY the publish stores are outstanding ----
        asm volatile("s_waitcnt vmcnt(0)" ::: "memory");
        __builtin_amdgcn_sched_barrier(0);
        __syncthreads();   // (A) all waves' publishes at coherence point
        if (tid == 0)
            __hip_atomic_store(flags_cl + w, (uint_t)(t + 1),
                               __ATOMIC_RELAXED, __HIP_MEMORY_SCOPE_AGENT);

        // ---- off-critical-path: out store + x(t+1) issue ----
        out[((size_t)(b0 + gb) * T_ + t) * H_ + hc0 + hcl] = hout;
        if (t + 1 < T_) {
            const float4_* p = (const float4_*)(xbase + (size_t)(t + 1) * D_);
            xq0 = p[0]; xq1 = p[1];
        }

        if (t + 1 < T_) {
            ushort_t* zn = z2[(t + 1) & 1];

            // ---- sleep-paced flag poll: ONE 64B line, divergent per-lane exit ----
            if (lane < WPC) {
                const uint_t* fp = flags_cl + lane;
                while (__hip_atomic_load(fp, __ATOMIC_RELAXED,
                                         __HIP_MEMORY_SCOPE_AGENT) <= (uint_t)t)
                    __builtin_amdgcn_s_sleep(1);
            }

            // ---- gather: 8 coalesced u32 (fresh: flags imply drained) ----
            const uint_t* hs = (((t + 1) & 1) ? hex1 : hex0);
            uint_t hv[8];
#pragma unroll
            for (int b = 0; b < 8; ++b)
                hv[b] = __hip_atomic_load(hs + b * 256 + tid,
                                          __ATOMIC_RELAXED, __HIP_MEMORY_SCOPE_AGENT);
            // thread holds h-cols {2*tid, 2*tid+1} for batches b=0..7
#pragma unroll
            for (int b = 0; b < 8; ++b)
                *(uint_t*)(zn + b * ZW + ((blk0 ^ b) << 3) + off2) = hv[b];

            // ---- zbuild x(t+1): x loads arrived during poll+gather ----
            {
                short8 a;
#pragma unroll
                for (int e = 0; e < 4; ++e) {
                    a[e]     = (short)f2bf(xq0[e]);
                    a[4 + e] = (short)f2bf(xq1[e]);
                }
                *(short8*)(zn + bx * ZW + ((ch ^ (bx & 7)) << 3)) = a;
            }
        }

        __syncthreads();   // (B) z(t+1) ready; z(t) free next iter
    }
}

extern "C" void kernel_launch(void* const* d_in, const int* in_sizes, int n_in,
                              void* d_out, int out_size, void* d_ws, size_t ws_size,
                              hipStream_t stream) {
    const float* x  = (const float*)d_in[0];
    const float* Wf = (const float*)d_in[1];
    const float* bf = (const float*)d_in[2];
    const float* Wi = (const float*)d_in[3];
    const float* bi = (const float*)d_in[4];
    const float* Wo = (const float*)d_in[5];
    const float* bo = (const float*)d_in[6];
    const float* Wc = (const float*)d_in[7];
    const float* bc = (const float*)d_in[8];
    float* out = (float*)d_out;

    // workspace: [0, 512)        flags [8][16] u32 -- zeroed per launch
    //            [4096, +131072) hexch [2][8][8][256] u32 (gated by flags+drain)
    uint_t* flags = (uint_t*)d_ws;
    uint_t* hexch = (uint_t*)((char*)d_ws + 4096);

    hipMemsetAsync(d_ws, 0, 4096, stream);   // flags

    lstm_persistent<<<dim3(NCL * WPC), dim3(256), 0, stream>>>(
        x, Wf, bf, Wi, bi, Wo, bo, Wc, bc, out, flags, hexch);
}